// Round 1
// baseline (1022.838 us; speedup 1.0000x reference)
//
#include <hip/hip_runtime.h>
#include <hip/hip_bf16.h>
#include <stdint.h>

#define VOCAB 50257
#define NPAD  50304   // 393*128, padded N for the GEMM
#define D 768
#define E 4
#define R 32
#define B 4
#define T 512
#define NTOK (B*T)    // 2048

typedef float f32x4 __attribute__((ext_vector_type(4)));
typedef short s16x8 __attribute__((ext_vector_type(8)));

__device__ __forceinline__ void async16(const void* g, void* l) {
    __builtin_amdgcn_global_load_lds(
        (const __attribute__((address_space(1))) uint32_t*)g,
        (__attribute__((address_space(3))) uint32_t*)l, 16, 0, 0);
}

// ---------------- K1: embedding gather + routing + u = x @ W_in[e*] ----------
__global__ __launch_bounds__(256) void k_embed_route(
    const int* __restrict__ idx, const float* __restrict__ Wemb,
    const float* __restrict__ G, const float* __restrict__ Win,
    float* __restrict__ xbuf, int* __restrict__ winner, float* __restrict__ ubuf)
{
    int tok = blockIdx.x;
    int tid = threadIdx.x;
    __shared__ float xs[D];
    __shared__ float sc[E];
    __shared__ float up[8][R];

    int token = idx[tok];
    const float* wrow = Wemb + (size_t)token * D;
    float x0 = wrow[tid], x1 = wrow[tid + 256], x2 = wrow[tid + 512];
    xs[tid] = x0; xs[tid + 256] = x1; xs[tid + 512] = x2;
    float* xg = xbuf + (size_t)tok * D;
    xg[tid] = x0; xg[tid + 256] = x1; xg[tid + 512] = x2;
    __syncthreads();

    // routing scores: wave w computes expert w's dot
    int wave = tid >> 6, lane = tid & 63;
    {
        const float* g = G + wave * D;
        float p = 0.f;
        for (int d = lane; d < D; d += 64) p += xs[d] * g[d];
        for (int off = 32; off; off >>= 1) p += __shfl_down(p, off);
        if (lane == 0) sc[wave] = p;
    }
    __syncthreads();
    float s0 = sc[0], s1 = sc[1], s2 = sc[2], s3 = sc[3];
    int e = 0; float best = s0;                 // first-max (jnp.argmax) semantics
    if (s1 > best) { best = s1; e = 1; }
    if (s2 > best) { best = s2; e = 2; }
    if (s3 > best) { best = s3; e = 3; }
    if (tid == 0) winner[tok] = e;

    // u[r] = sum_d x[d] * W_in[e][d][r]; 8 d-chunks x 32 r
    int r = tid & 31, chunk = tid >> 5;
    const float* wi = Win + (size_t)e * D * R;
    float p = 0.f;
    int d0 = chunk * 96;
    for (int d = d0; d < d0 + 96; ++d) p += xs[d] * wi[d * R + r];
    up[chunk][r] = p;
    __syncthreads();
    if (tid < R) {
        float s = 0.f;
        #pragma unroll
        for (int ch = 0; ch < 8; ++ch) s += up[ch][tid];
        ubuf[(size_t)tok * R + tid] = s;
    }
}

// ---------------- K2: sequential scan (one wave per batch) -------------------
__global__ __launch_bounds__(64) void k_scan(
    const int* __restrict__ winner, const float* __restrict__ ubuf,
    const float* __restrict__ Wrec, float* __restrict__ cbuf)
{
    int b = blockIdx.x;
    int j = threadIdx.x;          // lane; only j<32 active in the loop
    __shared__ float s_lds[E * R];
    s_lds[j] = 0.f; s_lds[j + 64] = 0.f;

    float wr0[R], wr1[R], wr2[R], wr3[R];   // W_rec column j per expert, in VGPRs
    if (j < R) {
        #pragma unroll
        for (int i = 0; i < R; ++i) {
            wr0[i] = Wrec[0 * R * R + i * R + j];
            wr1[i] = Wrec[1 * R * R + i * R + j];
            wr2[i] = Wrec[2 * R * R + i * R + j];
            wr3[i] = Wrec[3 * R * R + i * R + j];
        }
    }
    __syncthreads();
    if (j >= R) return;

    const int*   wb = winner + b * T;
    const float* ub = ubuf + (size_t)b * T * R;
    float*       cb = cbuf + (size_t)b * T * R;

    int   e_n = wb[0];
    float u_n = ub[j];
    for (int t = 0; t < T; ++t) {
        int e = e_n; float uj = u_n;
        if (t + 1 < T) { e_n = wb[t + 1]; u_n = ub[(t + 1) * R + j]; }  // prefetch

        const float* sp = &s_lds[e * R];
        float a0 = uj, a1 = 0.f, a2 = 0.f, a3 = 0.f;
        #define ACCLOOP(WR)                                              \
            _Pragma("unroll")                                            \
            for (int q = 0; q < 8; ++q) {                                \
                float4 sv = *(const float4*)&sp[q * 4];                  \
                a0 += sv.x * WR[q * 4 + 0]; a1 += sv.y * WR[q * 4 + 1];  \
                a2 += sv.z * WR[q * 4 + 2]; a3 += sv.w * WR[q * 4 + 3];  \
            }
        if      (e == 0) { ACCLOOP(wr0) }
        else if (e == 1) { ACCLOOP(wr1) }
        else if (e == 2) { ACCLOOP(wr2) }
        else             { ACCLOOP(wr3) }
        #undef ACCLOOP
        float acc = (a0 + a1) + (a2 + a3);
        // tanh(x) = 1 - 2/(exp(2x)+1); stable at +/-inf with rcp
        float ex = __expf(2.f * acc);
        float th = 1.f - 2.f * __builtin_amdgcn_rcpf(ex + 1.f);
        cb[t * R + j] = th;
        s_lds[e * R + j] = th;    // winner's state update; program order within wave
    }
}

// ---------------- K3: y = c @ W_out[e*] + x; LayerNorm; -> bf16 h ------------
__global__ __launch_bounds__(256) void k_out_ln(
    const float* __restrict__ xbuf, const int* __restrict__ winner,
    const float* __restrict__ cbuf, const float* __restrict__ Wout,
    const float* __restrict__ gamma, const float* __restrict__ beta,
    __hip_bfloat16* __restrict__ hbuf)
{
    int tok = blockIdx.x, tid = threadIdx.x;
    __shared__ float cs[R];
    __shared__ float w1[4], w2[4];
    int e = winner[tok];
    if (tid < R) cs[tid] = cbuf[(size_t)tok * R + tid];
    __syncthreads();

    const float* wo = Wout + (size_t)e * R * D;
    const float* xg = xbuf + (size_t)tok * D;
    float y[3];
    #pragma unroll
    for (int kk = 0; kk < 3; ++kk) {
        int d = tid + kk * 256;
        float acc = xg[d];
        #pragma unroll
        for (int r = 0; r < R; ++r) acc += cs[r] * wo[r * D + d];
        y[kk] = acc;
    }
    float s1 = y[0] + y[1] + y[2];
    float s2 = y[0] * y[0] + y[1] * y[1] + y[2] * y[2];
    int wave = tid >> 6, lane = tid & 63;
    for (int off = 32; off; off >>= 1) { s1 += __shfl_down(s1, off); s2 += __shfl_down(s2, off); }
    if (lane == 0) { w1[wave] = s1; w2[wave] = s2; }
    __syncthreads();
    float m = (w1[0] + w1[1] + w1[2] + w1[3]) * (1.f / D);
    float v = (w2[0] + w2[1] + w2[2] + w2[3]) * (1.f / D) - m * m;
    float rstd = rsqrtf(v + 1e-5f);
    #pragma unroll
    for (int kk = 0; kk < 3; ++kk) {
        int d = tid + kk * 256;
        float hn = (y[kk] - m) * rstd * gamma[d] + beta[d];
        hbuf[(size_t)tok * D + d] = __float2bfloat16(hn);
    }
}

// ---------------- K4: W_emb fp32 -> bf16 (padded to NPAD rows) ---------------
__global__ __launch_bounds__(256) void k_cvt(
    const float* __restrict__ Wemb, __hip_bfloat16* __restrict__ Wb)
{
    long i = (long)(blockIdx.x * 256 + threadIdx.x) * 4;
    const long total = (long)NPAD * D;
    const long valid = (long)VOCAB * D;
    if (i >= total) return;
    float4 v;
    if (i < valid) v = *(const float4*)(Wemb + i);
    else           v = make_float4(0.f, 0.f, 0.f, 0.f);
    union { ushort4 u4; __hip_bfloat16 h[4]; } pk;
    pk.h[0] = __float2bfloat16(v.x); pk.h[1] = __float2bfloat16(v.y);
    pk.h[2] = __float2bfloat16(v.z); pk.h[3] = __float2bfloat16(v.w);
    *(ushort4*)((unsigned short*)Wb + i) = pk.u4;
}

// ---------------- K5: logits = h @ Wemb^T  (bf16 MFMA, m97 structure) --------
#define BM 128
#define BN 128
#define BK 64
__global__ __launch_bounds__(256) void k_gemm(
    const __hip_bfloat16* __restrict__ A,   // [2048][768]  (h)
    const __hip_bfloat16* __restrict__ Bm,  // [NPAD][768]  (W_emb bf16, B^T layout)
    float* __restrict__ Cmat)               // [2048][VOCAB]
{
    __shared__ __align__(16) char lds[BM * BK * 2 + BN * BK * 2];  // 16KB + 16KB
    const int tid = threadIdx.x;
    const int m0 = blockIdx.x * BM;        // M fastest -> same-N blocks co-resident (L2 B reuse)
    const int n0 = blockIdx.y * BN;
    const int wave = tid >> 6, lane = tid & 63;
    const int wm = (wave >> 1) * 64, wn = (wave & 1) * 64;
    const int l15 = lane & 15, quad = lane >> 4;

    f32x4 acc[4][4] = {};

    const int srow = tid >> 3;             // 0..31 (+32 per round)
    const int skel = (tid & 7) * 8;        // k element offset within BK
    const size_t aBase = (size_t)(m0 + srow) * 768 + skel;
    const size_t bBase = (size_t)(n0 + srow) * 768 + skel;
    char* aT = lds;
    char* bT = lds + BM * BK * 2;
    const int ldsOff = tid * 16;

    for (int k0 = 0; k0 < 768; k0 += BK) {
        #pragma unroll
        for (int rr = 0; rr < 4; ++rr) {
            async16(A  + aBase + (size_t)rr * 32 * 768 + k0, aT + rr * 4096 + ldsOff);
            async16(Bm + bBase + (size_t)rr * 32 * 768 + k0, bT + rr * 4096 + ldsOff);
        }
        __syncthreads();
        #pragma unroll
        for (int kk = 0; kk < BK; kk += 32) {
            s16x8 af[4], bf[4];
            #pragma unroll
            for (int i = 0; i < 4; ++i)
                af[i] = *(const s16x8*)(aT + ((wm + i * 16 + l15) * BK + kk + quad * 8) * 2);
            #pragma unroll
            for (int j = 0; j < 4; ++j)
                bf[j] = *(const s16x8*)(bT + ((wn + j * 16 + l15) * BK + kk + quad * 8) * 2);
            #pragma unroll
            for (int i = 0; i < 4; ++i)
                #pragma unroll
                for (int j = 0; j < 4; ++j)
                    acc[i][j] = __builtin_amdgcn_mfma_f32_16x16x32_bf16(af[i], bf[j], acc[i][j], 0, 0, 0);
        }
        __syncthreads();
    }

    // epilogue: C/D layout col=lane&15, row=quad*4+reg (m89/m91-verified)
    #pragma unroll
    for (int i = 0; i < 4; ++i) {
        #pragma unroll
        for (int j = 0; j < 4; ++j) {
            int col = n0 + wn + j * 16 + l15;
            if (col < VOCAB) {
                #pragma unroll
                for (int r = 0; r < 4; ++r) {
                    int row = m0 + wm + i * 16 + quad * 4 + r;
                    Cmat[(size_t)row * VOCAB + col] = acc[i][j][r];
                }
            }
        }
    }
}

extern "C" void kernel_launch(void* const* d_in, const int* in_sizes, int n_in,
                              void* d_out, int out_size, void* d_ws, size_t ws_size,
                              hipStream_t stream)
{
    const int*   idx   = (const int*)d_in[0];
    const float* Wemb  = (const float*)d_in[1];
    const float* G     = (const float*)d_in[2];
    const float* Win   = (const float*)d_in[3];
    const float* Wrec  = (const float*)d_in[4];
    const float* Wout  = (const float*)d_in[5];
    const float* gamma = (const float*)d_in[6];
    const float* beta  = (const float*)d_in[7];
    float* out = (float*)d_out;

    char* ws = (char*)d_ws;
    float*          xbuf   = (float*)(ws);                    // 6,291,456 B
    int*            winner = (int*)  (ws + 6291456);          // 8,192 B
    float*          ubuf   = (float*)(ws + 6299648);          // 262,144 B
    float*          cbuf   = (float*)(ws + 6561792);          // 262,144 B
    __hip_bfloat16* hbuf   = (__hip_bfloat16*)(ws + 6823936); // 3,145,728 B
    __hip_bfloat16* wembb  = (__hip_bfloat16*)(ws + 9969664); // 77,266,944 B (total ~87.2 MB)

    k_cvt<<<(NPAD * D / 4 + 255) / 256, 256, 0, stream>>>(Wemb, wembb);
    k_embed_route<<<NTOK, 256, 0, stream>>>(idx, Wemb, G, Win, xbuf, winner, ubuf);
    k_scan<<<B, 64, 0, stream>>>(winner, ubuf, Wrec, cbuf);
    k_out_ln<<<NTOK, 256, 0, stream>>>(xbuf, winner, cbuf, Wout, gamma, beta, hbuf);
    k_gemm<<<dim3(16, 393), 256, 0, stream>>>(hbuf, wembb, out);
}